// Round 1
// 366.810 us; speedup vs baseline: 1.0173x; 1.0173x over previous
//
#include <hip/hip_runtime.h>
#include <hip/hip_bf16.h>

typedef __hip_bfloat16 bf16;
typedef __attribute__((ext_vector_type(8))) short bf16x8v;   // 8 bf16 (4 VGPRs) MFMA operand
typedef __attribute__((ext_vector_type(4))) float f32x4;     // MFMA accumulator
typedef __attribute__((ext_vector_type(4))) short short4v;   // 8B packed bf16 store

#define B_SZ   2048
#define NSTEP  128
#define DD     100
#define DX     100
#define DH     256

#define UCOLS  104          // 100 x-dims + t + 3 zero pad (global U layout)

__device__ __constant__ const float DT_   = 0.0078125f;              // 1/128
__device__ __constant__ const float SQDT_ = 0.08838834764831845f;    // sqrt(1/128)
// sqrt(2)*sqrt(dt) = sqrt(2/128) = 1/8 exactly
__device__ __constant__ const float C1_   = 0.125f;

// ---------------------------------------------------------------------------
// Kernel 1: per-batch prefix sums of noise -> build U rows (bf16) + final x
// U row p = (b*128 + i)*2 + h ; cols 0..99 = x-part, col 100 = t, 101..103 = 0
// ---------------------------------------------------------------------------
__global__ __launch_bounds__(128) void prep_kernel(
    const float* __restrict__ Wn, const int* __restrict__ signs,
    const float* __restrict__ x0,
    bf16* __restrict__ U, float* __restrict__ xout)
{
    __shared__ float w_l[DD * 129];   // padded stride 129 -> conflict-free
    __shared__ float s_l[NSTEP];
    const int b = blockIdx.x, tid = threadIdx.x;
    const float* wb = Wn + (size_t)b * DD * NSTEP;

    for (int idx = tid; idx < DD * NSTEP; idx += 128) {
        int d = idx >> 7, i = idx & 127;
        w_l[d * 129 + i] = wb[idx];
    }
    if (tid < NSTEP) s_l[tid] = 2.f * (float)signs[tid] - 1.f;
    __syncthreads();

    if (tid < DD) {
        const int d = tid;
        float x = x0[d];
        for (int i = 0; i < NSTEP; ++i) {
            size_t p = ((size_t)(b * NSTEP + i)) * 2;
            float wn = w_l[d * 129 + i];
            U[p * UCOLS + d]       = __float2bfloat16(x);
            U[(p + 1) * UCOLS + d] = __float2bfloat16(x + C1_ * (wn - s_l[i]));
            x += C1_ * wn;
        }
        xout[(size_t)b * DX + d] = x;   // exact f32 final x
    } else if (tid < UCOLS) {
        for (int i = 0; i < NSTEP; ++i) {
            size_t p = ((size_t)(b * NSTEP + i)) * 2;
            float v0 = 0.f, v1 = 0.f;
            if (tid == 100) { v0 = DT_ * (float)i; v1 = DT_ * (float)(i + 1); }
            U[p * UCOLS + tid]       = __float2bfloat16(v0);
            U[(p + 1) * UCOLS + tid] = __float2bfloat16(v1);
        }
    }
}

// ---------------------------------------------------------------------------
// Weight fragment packing: W[Kact][Nact] f32 -> bf16 A-frags of W^T.
// frag idx = ((t*KC + c)*64 + lane)*8 + j ; n = t*16+(lane&15), k = c*32+(lane>>4)*8+j
// Out-of-range (k,n) -> 0 (handles K=101->128 and N=100->128 padding).
// ---------------------------------------------------------------------------
__global__ __launch_bounds__(256) void wpack_kernel(
    const float* __restrict__ W, bf16* __restrict__ dst,
    int Kact, int Nact, int KC, int total)
{
    int idx = blockIdx.x * 256 + threadIdx.x;
    if (idx >= total) return;
    int j = idx & 7;
    int l = (idx >> 3) & 63;
    int c = (idx >> 9) % KC;
    int t = idx / (KC * 512);
    int n = t * 16 + (l & 15);
    int k = c * 32 + (l >> 4) * 8 + j;
    float v = (k < Kact && n < Nact) ? W[(size_t)k * Nact + n] : 0.f;
    dst[idx] = __float2bfloat16(v);
}

// Pack biases into one padded f32 buffer: [0:256)=bi [256:512)=bh1 [512:768)=bh2 [768:896)=bo(pad0)
__global__ __launch_bounds__(256) void bpack_kernel(
    const float* __restrict__ bi, const float* __restrict__ bh1,
    const float* __restrict__ bh2, const float* __restrict__ bo,
    float* __restrict__ dst)
{
    int i = blockIdx.x * 256 + threadIdx.x;
    if (i < 256) dst[i] = bi[i];
    else if (i < 512) dst[i] = bh1[i - 256];
    else if (i < 768) dst[i] = bh2[i - 512];
    else if (i < 896) dst[i] = (i - 768 < DD) ? bo[i - 768] : 0.f;
}

// ---------------------------------------------------------------------------
// One MFMA layer, IN PLACE in a single LDS buffer:
//   phase 1: accumulate D[n][m] = W^T x act entirely into registers (reads buf)
//   __syncthreads()  -> every wave in the block has finished reading buf
//   phase 2: bias+relu+pack, store outputs back into buf (possibly new stride)
// Caller must __syncthreads() after return before the next layer reads.
// This halves LDS vs ping-pong buffers -> 4 blocks/CU instead of 2.
// Wave w owns n-tiles [w*NT, w*NT+NT), all 64 m-rows (4 m-tiles).
// ---------------------------------------------------------------------------
template<int KC, int NT, int SRC_STRIDE, int DST_STRIDE, bool RELU>
__device__ __forceinline__ void layer_ip(
    char* __restrict__ buf,
    const bf16* __restrict__ wfrag, const float* __restrict__ bias,
    int lane, int w)
{
    const int lrow = lane & 15;   // m_local (B col) / n_local (A row)
    const int lkg  = lane >> 4;   // k-group
    f32x4 acc[NT][4];
#pragma unroll
    for (int t = 0; t < NT; ++t)
#pragma unroll
        for (int mt = 0; mt < 4; ++mt) acc[t][mt] = (f32x4){0.f, 0.f, 0.f, 0.f};

    const char* wptr = (const char*)wfrag + ((size_t)(w * NT) * KC * 64 + lane) * 16;

    for (int c = 0; c < KC; ++c) {
        bf16x8v b[4];
#pragma unroll
        for (int mt = 0; mt < 4; ++mt) {
            int m = mt * 16 + lrow;
            b[mt] = *(const bf16x8v*)(buf + m * SRC_STRIDE +
                                      ((c * 64 + lkg * 16) ^ ((m & 7) << 4)));
        }
        __builtin_amdgcn_s_setprio(1);
#pragma unroll
        for (int t = 0; t < NT; ++t) {
            bf16x8v a = *(const bf16x8v*)(wptr + (t * KC + c) * 1024);
#pragma unroll
            for (int mt = 0; mt < 4; ++mt)
                acc[t][mt] = __builtin_amdgcn_mfma_f32_16x16x32_bf16(a, b[mt], acc[t][mt], 0, 0, 0);
        }
        __builtin_amdgcn_s_setprio(0);
    }

    __syncthreads();   // all reads of buf complete block-wide; safe to overwrite

#pragma unroll
    for (int t = 0; t < NT; ++t) {
        const int nb = (w * NT + t) * 16 + lkg * 4;   // first of 4 consecutive features
        const float4 bv = *(const float4*)(bias + nb);
#pragma unroll
        for (int mt = 0; mt < 4; ++mt) {
            const int m = mt * 16 + lrow;
            float v0 = acc[t][mt][0] + bv.x;
            float v1 = acc[t][mt][1] + bv.y;
            float v2 = acc[t][mt][2] + bv.z;
            float v3 = acc[t][mt][3] + bv.w;
            if (RELU) {
                v0 = fmaxf(v0, 0.f); v1 = fmaxf(v1, 0.f);
                v2 = fmaxf(v2, 0.f); v3 = fmaxf(v3, 0.f);
            }
            bf16 h0 = __float2bfloat16(v0), h1 = __float2bfloat16(v1);
            bf16 h2 = __float2bfloat16(v2), h3 = __float2bfloat16(v3);
            short4v pv;
            pv[0] = *(short*)&h0; pv[1] = *(short*)&h1;
            pv[2] = *(short*)&h2; pv[3] = *(short*)&h3;
            *(short4v*)(buf + m * DST_STRIDE + ((nb * 2) ^ ((m & 7) << 4))) = pv;
        }
    }
}

// ---------------------------------------------------------------------------
// Kernel 2: fused 4-layer MFMA MLP over 64 rows + per-pair y-increment
// Single 32KB activation buffer (in-place layers) -> 33280B LDS -> 4 blocks/CU.
// __launch_bounds__(256,4): 4 waves/EU -> VGPR capped at 128 (currently 116).
// ---------------------------------------------------------------------------
__global__ __launch_bounds__(256, 4) void mlp_mfma_kernel(
    const bf16* __restrict__ U,
    const float* __restrict__ Wn, const int* __restrict__ signs,
    const bf16* __restrict__ wfWi, const bf16* __restrict__ wfWh1,
    const bf16* __restrict__ wfWh2, const bf16* __restrict__ wfWo,
    const float* __restrict__ biases, float* __restrict__ incr)
{
    __shared__ char buf[64 * 512];
    __shared__ float Sz2[64], Szw[64];
    const int tid = threadIdx.x;
    const int lane = tid & 63, w = tid >> 6;
    const size_t row0 = (size_t)blockIdx.x * 64;

    // Load U tile: 64 rows x 104 bf16 = 13 x 16B chunks/row -> buf [64][128] stride 256B,
    // swizzled; chunks 13..15 zero-filled (k padding must be 0, not garbage).
    {
        const char* usrc = (const char*)(U + row0 * UCOLS);
        for (int idx = tid; idx < 1024; idx += 256) {
            if (idx < 832) {
                int r = idx / 13, c = idx - r * 13;
                uint4 v = *(const uint4*)(usrc + r * 208 + c * 16);
                *(uint4*)(buf + r * 256 + ((c * 16) ^ ((r & 7) << 4))) = v;
            } else {
                int i2 = idx - 832;
                int r = i2 & 63, c = 13 + (i2 >> 6);
                *(uint4*)(buf + r * 256 + ((c * 16) ^ ((r & 7) << 4))) = (uint4){0, 0, 0, 0};
            }
        }
    }
    __syncthreads();

    layer_ip<4, 4, 256, 512, true >(buf, wfWi,  biases,        lane, w);
    __syncthreads();
    layer_ip<8, 4, 512, 512, true >(buf, wfWh1, biases + 256,  lane, w);
    __syncthreads();
    layer_ip<8, 4, 512, 512, true >(buf, wfWh2, biases + 512,  lane, w);
    __syncthreads();
    layer_ip<8, 2, 512, 256, false>(buf, wfWo,  biases + 768,  lane, w);
    __syncthreads();
    // z rows now in buf [64][128] stride 256B (features 0..99 valid)

    // Per-row reductions: 4 threads per row
    const int r = tid >> 2, q = tid & 3;
    const size_t g = row0 + r;
    const size_t pair = g >> 1;
    const int h = (int)(g & 1);
    const int bb = (int)(pair >> 7), ii = (int)(pair & 127);
    const float s = 2.f * (float)signs[ii] - 1.f;
    const float sdt = s * SQDT_;
    const float* wb = Wn + (size_t)bb * DD * NSTEP + ii;

    float sz2 = 0.f, szw = 0.f;
    for (int d = q; d < DD; d += 4) {
        unsigned short zb = *(const unsigned short*)(buf + r * 256 + ((d * 2) ^ ((r & 7) << 4)));
        union { unsigned int u; float f; } cv; cv.u = ((unsigned int)zb) << 16;
        float z = cv.f;
        float wv = SQDT_ * wb[(size_t)d * NSTEP];
        float wt = h ? (wv + sdt) : (wv - sdt);
        sz2 += z * z;
        szw += z * wt;
    }
    sz2 += __shfl_xor(sz2, 1); sz2 += __shfl_xor(sz2, 2);
    szw += __shfl_xor(szw, 1); szw += __shfl_xor(szw, 2);
    if (q == 0) { Sz2[r] = sz2; Szw[r] = szw; }
    __syncthreads();

    // incr = -||z||^2*dt + 0.5*(z.(w-sdt) + z_new.(w+sdt));  z from h=0 row
    if (tid < 32) {
        int rr = tid * 2;
        incr[row0 / 2 + tid] = -Sz2[rr] * DT_ + 0.5f * (Szw[rr] + Szw[rr + 1]);
    }
}

// ---------------------------------------------------------------------------
// Kernel 3: y[b] = y0 + sum_i incr[b*128+i]
// ---------------------------------------------------------------------------
__global__ __launch_bounds__(128) void y_kernel(
    const float* __restrict__ incr, const float* __restrict__ y0,
    float* __restrict__ yout)
{
    const int b = blockIdx.x, tid = threadIdx.x;
    float v = incr[(size_t)b * NSTEP + tid];
#pragma unroll
    for (int off = 1; off < 64; off <<= 1) v += __shfl_xor(v, off);
    __shared__ float partial[2];
    if ((tid & 63) == 0) partial[tid >> 6] = v;
    __syncthreads();
    if (tid == 0) yout[b] = y0[0] + partial[0] + partial[1];
}

// ---------------------------------------------------------------------------
extern "C" void kernel_launch(void* const* d_in, const int* in_sizes, int n_in,
                              void* d_out, int out_size, void* d_ws, size_t ws_size,
                              hipStream_t stream) {
    (void)in_sizes; (void)n_in; (void)out_size; (void)ws_size;
    const float* Wn    = (const float*)d_in[0];
    const int*   signs = (const int*)d_in[1];
    const float* x0    = (const float*)d_in[2];
    const float* y0    = (const float*)d_in[3];
    const float* Wi    = (const float*)d_in[4];
    const float* bi    = (const float*)d_in[5];
    const float* Wh1   = (const float*)d_in[6];
    const float* bh1   = (const float*)d_in[7];
    const float* Wh2   = (const float*)d_in[8];
    const float* bh2   = (const float*)d_in[9];
    const float* Wo    = (const float*)d_in[10];
    const float* bo    = (const float*)d_in[11];

    float* out  = (float*)d_out;
    float* xout = out;                       // [2048,100]
    float* yout = out + (size_t)B_SZ * DX;   // [2048,1]

    const size_t NROWS = (size_t)B_SZ * NSTEP * 2;           // 524288
    char* ws = (char*)d_ws;
    size_t off = 0;
    bf16*  U      = (bf16*)(ws + off); off += NROWS * UCOLS * sizeof(bf16);   // ~109 MB
    float* incr   = (float*)(ws + off); off += (NROWS / 2) * sizeof(float);   // 1 MB
    bf16*  wfWi   = (bf16*)(ws + off); off += 32768 * sizeof(bf16);
    bf16*  wfWh1  = (bf16*)(ws + off); off += 65536 * sizeof(bf16);
    bf16*  wfWh2  = (bf16*)(ws + off); off += 65536 * sizeof(bf16);
    bf16*  wfWo   = (bf16*)(ws + off); off += 32768 * sizeof(bf16);
    float* biases = (float*)(ws + off); off += 896 * sizeof(float);

    prep_kernel<<<B_SZ, 128, 0, stream>>>(Wn, signs, x0, U, xout);
    wpack_kernel<<<128, 256, 0, stream>>>(Wi,  wfWi,  101, 256, 4, 32768);
    wpack_kernel<<<256, 256, 0, stream>>>(Wh1, wfWh1, 256, 256, 8, 65536);
    wpack_kernel<<<256, 256, 0, stream>>>(Wh2, wfWh2, 256, 256, 8, 65536);
    wpack_kernel<<<128, 256, 0, stream>>>(Wo,  wfWo,  256, 100, 8, 32768);
    bpack_kernel<<<4, 256, 0, stream>>>(bi, bh1, bh2, bo, biases);

    mlp_mfma_kernel<<<(int)(NROWS / 64), 256, 0, stream>>>(
        U, Wn, signs, wfWi, wfWh1, wfWh2, wfWo, biases, incr);
    y_kernel<<<B_SZ, 128, 0, stream>>>(incr, y0, yout);
}

// Round 2
// 334.987 us; speedup vs baseline: 1.1140x; 1.0950x over previous
//
#include <hip/hip_runtime.h>
#include <hip/hip_bf16.h>

typedef __hip_bfloat16 bf16;
typedef __attribute__((ext_vector_type(8))) short bf16x8v;   // 8 bf16 (4 VGPRs) MFMA operand
typedef __attribute__((ext_vector_type(4))) float f32x4;     // MFMA accumulator
typedef __attribute__((ext_vector_type(4))) short short4v;   // 8B packed bf16 store

#define B_SZ   2048
#define NSTEP  128
#define DD     100
#define DX     100
#define DH     256

#define UCOLS  104          // 100 x-dims + t + 3 zero pad (global U layout)

__device__ __constant__ const float DT_   = 0.0078125f;              // 1/128
__device__ __constant__ const float SQDT_ = 0.08838834764831845f;    // sqrt(1/128)
// sqrt(2)*sqrt(dt) = sqrt(2/128) = 1/8 exactly
__device__ __constant__ const float C1_   = 0.125f;

// ---------------------------------------------------------------------------
// Kernel 1: per-batch prefix sums of noise -> build U rows (bf16) + final x
// U row p = (b*128 + i)*2 + h ; cols 0..99 = x-part, col 100 = t, 101..103 = 0
// ---------------------------------------------------------------------------
__global__ __launch_bounds__(128) void prep_kernel(
    const float* __restrict__ Wn, const int* __restrict__ signs,
    const float* __restrict__ x0,
    bf16* __restrict__ U, float* __restrict__ xout)
{
    __shared__ float w_l[DD * 129];   // padded stride 129 -> conflict-free
    __shared__ float s_l[NSTEP];
    const int b = blockIdx.x, tid = threadIdx.x;
    const float* wb = Wn + (size_t)b * DD * NSTEP;

    for (int idx = tid; idx < DD * NSTEP; idx += 128) {
        int d = idx >> 7, i = idx & 127;
        w_l[d * 129 + i] = wb[idx];
    }
    if (tid < NSTEP) s_l[tid] = 2.f * (float)signs[tid] - 1.f;
    __syncthreads();

    if (tid < DD) {
        const int d = tid;
        float x = x0[d];
        for (int i = 0; i < NSTEP; ++i) {
            size_t p = ((size_t)(b * NSTEP + i)) * 2;
            float wn = w_l[d * 129 + i];
            U[p * UCOLS + d]       = __float2bfloat16(x);
            U[(p + 1) * UCOLS + d] = __float2bfloat16(x + C1_ * (wn - s_l[i]));
            x += C1_ * wn;
        }
        xout[(size_t)b * DX + d] = x;   // exact f32 final x
    } else if (tid < UCOLS) {
        for (int i = 0; i < NSTEP; ++i) {
            size_t p = ((size_t)(b * NSTEP + i)) * 2;
            float v0 = 0.f, v1 = 0.f;
            if (tid == 100) { v0 = DT_ * (float)i; v1 = DT_ * (float)(i + 1); }
            U[p * UCOLS + tid]       = __float2bfloat16(v0);
            U[(p + 1) * UCOLS + tid] = __float2bfloat16(v1);
        }
    }
}

// ---------------------------------------------------------------------------
// Weight fragment packing: W[Kact][Nact] f32 -> bf16 A-frags of W^T.
// frag idx = ((t*KC + c)*64 + lane)*8 + j ; n = t*16+(lane&15), k = c*32+(lane>>4)*8+j
// Out-of-range (k,n) -> 0 (handles K=101->128 and N=100->128 padding).
// ---------------------------------------------------------------------------
__global__ __launch_bounds__(256) void wpack_kernel(
    const float* __restrict__ W, bf16* __restrict__ dst,
    int Kact, int Nact, int KC, int total)
{
    int idx = blockIdx.x * 256 + threadIdx.x;
    if (idx >= total) return;
    int j = idx & 7;
    int l = (idx >> 3) & 63;
    int c = (idx >> 9) % KC;
    int t = idx / (KC * 512);
    int n = t * 16 + (l & 15);
    int k = c * 32 + (l >> 4) * 8 + j;
    float v = (k < Kact && n < Nact) ? W[(size_t)k * Nact + n] : 0.f;
    dst[idx] = __float2bfloat16(v);
}

// Pack biases into one padded f32 buffer: [0:256)=bi [256:512)=bh1 [512:768)=bh2 [768:896)=bo(pad0)
__global__ __launch_bounds__(256) void bpack_kernel(
    const float* __restrict__ bi, const float* __restrict__ bh1,
    const float* __restrict__ bh2, const float* __restrict__ bo,
    float* __restrict__ dst)
{
    int i = blockIdx.x * 256 + threadIdx.x;
    if (i < 256) dst[i] = bi[i];
    else if (i < 512) dst[i] = bh1[i - 256];
    else if (i < 768) dst[i] = bh2[i - 512];
    else if (i < 896) dst[i] = (i - 768 < DD) ? bo[i - 768] : 0.f;
}

// ---------------------------------------------------------------------------
// One MFMA layer, IN PLACE in a single LDS buffer:
//   phase 1: accumulate D[n][m] = W^T x act entirely into registers (reads buf)
//   __syncthreads()  -> every wave in the block has finished reading buf
//   phase 2: bias+relu+pack, store outputs back into buf (possibly new stride)
// Caller must __syncthreads() after return before the next layer reads.
// Wave w owns n-tiles [w*NT, w*NT+NT), all 64 m-rows (4 m-tiles).
// ---------------------------------------------------------------------------
template<int KC, int NT, int SRC_STRIDE, int DST_STRIDE, bool RELU>
__device__ __forceinline__ void layer_ip(
    char* __restrict__ buf,
    const bf16* __restrict__ wfrag, const float* __restrict__ bias,
    int lane, int w)
{
    const int lrow = lane & 15;   // m_local (B col) / n_local (A row)
    const int lkg  = lane >> 4;   // k-group
    f32x4 acc[NT][4];
#pragma unroll
    for (int t = 0; t < NT; ++t)
#pragma unroll
        for (int mt = 0; mt < 4; ++mt) acc[t][mt] = (f32x4){0.f, 0.f, 0.f, 0.f};

    const char* wptr = (const char*)wfrag + ((size_t)(w * NT) * KC * 64 + lane) * 16;

    for (int c = 0; c < KC; ++c) {
        bf16x8v b[4];
#pragma unroll
        for (int mt = 0; mt < 4; ++mt) {
            int m = mt * 16 + lrow;
            b[mt] = *(const bf16x8v*)(buf + m * SRC_STRIDE +
                                      ((c * 64 + lkg * 16) ^ ((m & 7) << 4)));
        }
        __builtin_amdgcn_s_setprio(1);
#pragma unroll
        for (int t = 0; t < NT; ++t) {
            bf16x8v a = *(const bf16x8v*)(wptr + (t * KC + c) * 1024);
#pragma unroll
            for (int mt = 0; mt < 4; ++mt)
                acc[t][mt] = __builtin_amdgcn_mfma_f32_16x16x32_bf16(a, b[mt], acc[t][mt], 0, 0, 0);
        }
        __builtin_amdgcn_s_setprio(0);
    }

    __syncthreads();   // all reads of buf complete block-wide; safe to overwrite

#pragma unroll
    for (int t = 0; t < NT; ++t) {
        const int nb = (w * NT + t) * 16 + lkg * 4;   // first of 4 consecutive features
        const float4 bv = *(const float4*)(bias + nb);
#pragma unroll
        for (int mt = 0; mt < 4; ++mt) {
            const int m = mt * 16 + lrow;
            float v0 = acc[t][mt][0] + bv.x;
            float v1 = acc[t][mt][1] + bv.y;
            float v2 = acc[t][mt][2] + bv.z;
            float v3 = acc[t][mt][3] + bv.w;
            if (RELU) {
                v0 = fmaxf(v0, 0.f); v1 = fmaxf(v1, 0.f);
                v2 = fmaxf(v2, 0.f); v3 = fmaxf(v3, 0.f);
            }
            bf16 h0 = __float2bfloat16(v0), h1 = __float2bfloat16(v1);
            bf16 h2 = __float2bfloat16(v2), h3 = __float2bfloat16(v3);
            short4v pv;
            pv[0] = *(short*)&h0; pv[1] = *(short*)&h1;
            pv[2] = *(short*)&h2; pv[3] = *(short*)&h3;
            *(short4v*)(buf + m * DST_STRIDE + ((nb * 2) ^ ((m & 7) << 4))) = pv;
        }
    }
}

// ---------------------------------------------------------------------------
// Kernel 2: fused 4-layer MFMA MLP over 64 rows + per-pair y-increment
// Single 32KB activation buffer (in-place layers) -> 33280B LDS.
// __launch_bounds__(256,3): cap ~168 VGPR -> NO SPILL (the (256,4) variant
// spilled ~50 regs/thread: WRITE_SIZE 1MB->140MB, dur unchanged). acc[4][4]
// needs 64 regs + ~60 arch regs; if total lands <=128 the HW can still run
// 4 waves/SIMD, else a clean 3 waves/SIMD (12 waves/CU).
// ---------------------------------------------------------------------------
__global__ __launch_bounds__(256, 3) void mlp_mfma_kernel(
    const bf16* __restrict__ U,
    const float* __restrict__ Wn, const int* __restrict__ signs,
    const bf16* __restrict__ wfWi, const bf16* __restrict__ wfWh1,
    const bf16* __restrict__ wfWh2, const bf16* __restrict__ wfWo,
    const float* __restrict__ biases, float* __restrict__ incr)
{
    __shared__ char buf[64 * 512];
    __shared__ float Sz2[64], Szw[64];
    const int tid = threadIdx.x;
    const int lane = tid & 63, w = tid >> 6;
    const size_t row0 = (size_t)blockIdx.x * 64;

    // Load U tile: 64 rows x 104 bf16 = 13 x 16B chunks/row -> buf [64][128] stride 256B,
    // swizzled; chunks 13..15 zero-filled (k padding must be 0, not garbage).
    {
        const char* usrc = (const char*)(U + row0 * UCOLS);
        for (int idx = tid; idx < 1024; idx += 256) {
            if (idx < 832) {
                int r = idx / 13, c = idx - r * 13;
                uint4 v = *(const uint4*)(usrc + r * 208 + c * 16);
                *(uint4*)(buf + r * 256 + ((c * 16) ^ ((r & 7) << 4))) = v;
            } else {
                int i2 = idx - 832;
                int r = i2 & 63, c = 13 + (i2 >> 6);
                *(uint4*)(buf + r * 256 + ((c * 16) ^ ((r & 7) << 4))) = (uint4){0, 0, 0, 0};
            }
        }
    }
    __syncthreads();

    layer_ip<4, 4, 256, 512, true >(buf, wfWi,  biases,        lane, w);
    __syncthreads();
    layer_ip<8, 4, 512, 512, true >(buf, wfWh1, biases + 256,  lane, w);
    __syncthreads();
    layer_ip<8, 4, 512, 512, true >(buf, wfWh2, biases + 512,  lane, w);
    __syncthreads();
    layer_ip<8, 2, 512, 256, false>(buf, wfWo,  biases + 768,  lane, w);
    __syncthreads();
    // z rows now in buf [64][128] stride 256B (features 0..99 valid)

    // Per-row reductions: 4 threads per row
    const int r = tid >> 2, q = tid & 3;
    const size_t g = row0 + r;
    const size_t pair = g >> 1;
    const int h = (int)(g & 1);
    const int bb = (int)(pair >> 7), ii = (int)(pair & 127);
    const float s = 2.f * (float)signs[ii] - 1.f;
    const float sdt = s * SQDT_;
    const float* wb = Wn + (size_t)bb * DD * NSTEP + ii;

    float sz2 = 0.f, szw = 0.f;
    for (int d = q; d < DD; d += 4) {
        unsigned short zb = *(const unsigned short*)(buf + r * 256 + ((d * 2) ^ ((r & 7) << 4)));
        union { unsigned int u; float f; } cv; cv.u = ((unsigned int)zb) << 16;
        float z = cv.f;
        float wv = SQDT_ * wb[(size_t)d * NSTEP];
        float wt = h ? (wv + sdt) : (wv - sdt);
        sz2 += z * z;
        szw += z * wt;
    }
    sz2 += __shfl_xor(sz2, 1); sz2 += __shfl_xor(sz2, 2);
    szw += __shfl_xor(szw, 1); szw += __shfl_xor(szw, 2);
    if (q == 0) { Sz2[r] = sz2; Szw[r] = szw; }
    __syncthreads();

    // incr = -||z||^2*dt + 0.5*(z.(w-sdt) + z_new.(w+sdt));  z from h=0 row
    if (tid < 32) {
        int rr = tid * 2;
        incr[row0 / 2 + tid] = -Sz2[rr] * DT_ + 0.5f * (Szw[rr] + Szw[rr + 1]);
    }
}

// ---------------------------------------------------------------------------
// Kernel 3: y[b] = y0 + sum_i incr[b*128+i]
// ---------------------------------------------------------------------------
__global__ __launch_bounds__(128) void y_kernel(
    const float* __restrict__ incr, const float* __restrict__ y0,
    float* __restrict__ yout)
{
    const int b = blockIdx.x, tid = threadIdx.x;
    float v = incr[(size_t)b * NSTEP + tid];
#pragma unroll
    for (int off = 1; off < 64; off <<= 1) v += __shfl_xor(v, off);
    __shared__ float partial[2];
    if ((tid & 63) == 0) partial[tid >> 6] = v;
    __syncthreads();
    if (tid == 0) yout[b] = y0[0] + partial[0] + partial[1];
}

// ---------------------------------------------------------------------------
extern "C" void kernel_launch(void* const* d_in, const int* in_sizes, int n_in,
                              void* d_out, int out_size, void* d_ws, size_t ws_size,
                              hipStream_t stream) {
    (void)in_sizes; (void)n_in; (void)out_size; (void)ws_size;
    const float* Wn    = (const float*)d_in[0];
    const int*   signs = (const int*)d_in[1];
    const float* x0    = (const float*)d_in[2];
    const float* y0    = (const float*)d_in[3];
    const float* Wi    = (const float*)d_in[4];
    const float* bi    = (const float*)d_in[5];
    const float* Wh1   = (const float*)d_in[6];
    const float* bh1   = (const float*)d_in[7];
    const float* Wh2   = (const float*)d_in[8];
    const float* bh2   = (const float*)d_in[9];
    const float* Wo    = (const float*)d_in[10];
    const float* bo    = (const float*)d_in[11];

    float* out  = (float*)d_out;
    float* xout = out;                       // [2048,100]
    float* yout = out + (size_t)B_SZ * DX;   // [2048,1]

    const size_t NROWS = (size_t)B_SZ * NSTEP * 2;           // 524288
    char* ws = (char*)d_ws;
    size_t off = 0;
    bf16*  U      = (bf16*)(ws + off); off += NROWS * UCOLS * sizeof(bf16);   // ~109 MB
    float* incr   = (float*)(ws + off); off += (NROWS / 2) * sizeof(float);   // 1 MB
    bf16*  wfWi   = (bf16*)(ws + off); off += 32768 * sizeof(bf16);
    bf16*  wfWh1  = (bf16*)(ws + off); off += 65536 * sizeof(bf16);
    bf16*  wfWh2  = (bf16*)(ws + off); off += 65536 * sizeof(bf16);
    bf16*  wfWo   = (bf16*)(ws + off); off += 32768 * sizeof(bf16);
    float* biases = (float*)(ws + off); off += 896 * sizeof(float);

    prep_kernel<<<B_SZ, 128, 0, stream>>>(Wn, signs, x0, U, xout);
    wpack_kernel<<<128, 256, 0, stream>>>(Wi,  wfWi,  101, 256, 4, 32768);
    wpack_kernel<<<256, 256, 0, stream>>>(Wh1, wfWh1, 256, 256, 8, 65536);
    wpack_kernel<<<256, 256, 0, stream>>>(Wh2, wfWh2, 256, 256, 8, 65536);
    wpack_kernel<<<128, 256, 0, stream>>>(Wo,  wfWo,  256, 100, 8, 32768);
    bpack_kernel<<<4, 256, 0, stream>>>(bi, bh1, bh2, bo, biases);

    mlp_mfma_kernel<<<(int)(NROWS / 64), 256, 0, stream>>>(
        U, Wn, signs, wfWi, wfWh1, wfWh2, wfWo, biases, incr);
    y_kernel<<<B_SZ, 128, 0, stream>>>(incr, y0, yout);
}

// Round 3
// 320.802 us; speedup vs baseline: 1.1633x; 1.0442x over previous
//
#include <hip/hip_runtime.h>
#include <hip/hip_bf16.h>

typedef __hip_bfloat16 bf16;
typedef __attribute__((ext_vector_type(8))) short bf16x8v;   // 8 bf16 (4 VGPRs) MFMA operand
typedef __attribute__((ext_vector_type(4))) float f32x4;     // MFMA accumulator
typedef __attribute__((ext_vector_type(4))) short short4v;   // 8B packed bf16 store

#define B_SZ   2048
#define NSTEP  128
#define DD     100
#define DX     100
#define DH     256

#define UCOLS  104          // 100 x-dims + t + 3 zero pad (global U layout)

__device__ __constant__ const float DT_   = 0.0078125f;              // 1/128
__device__ __constant__ const float SQDT_ = 0.08838834764831845f;    // sqrt(1/128)
// sqrt(2)*sqrt(dt) = sqrt(2/128) = 1/8 exactly
__device__ __constant__ const float C1_   = 0.125f;

// ---------------------------------------------------------------------------
// Kernel 1: per-batch prefix sums of noise -> build U rows (bf16) + final x
// U row p = (b*128 + i)*2 + h ; cols 0..99 = x-part, col 100 = t, 101..103 = 0
// ---------------------------------------------------------------------------
__global__ __launch_bounds__(128) void prep_kernel(
    const float* __restrict__ Wn, const int* __restrict__ signs,
    const float* __restrict__ x0,
    bf16* __restrict__ U, float* __restrict__ xout)
{
    __shared__ float w_l[DD * 129];   // padded stride 129 -> conflict-free
    __shared__ float s_l[NSTEP];
    const int b = blockIdx.x, tid = threadIdx.x;
    const float* wb = Wn + (size_t)b * DD * NSTEP;

    for (int idx = tid; idx < DD * NSTEP; idx += 128) {
        int d = idx >> 7, i = idx & 127;
        w_l[d * 129 + i] = wb[idx];
    }
    if (tid < NSTEP) s_l[tid] = 2.f * (float)signs[tid] - 1.f;
    __syncthreads();

    if (tid < DD) {
        const int d = tid;
        float x = x0[d];
        for (int i = 0; i < NSTEP; ++i) {
            size_t p = ((size_t)(b * NSTEP + i)) * 2;
            float wn = w_l[d * 129 + i];
            U[p * UCOLS + d]       = __float2bfloat16(x);
            U[(p + 1) * UCOLS + d] = __float2bfloat16(x + C1_ * (wn - s_l[i]));
            x += C1_ * wn;
        }
        xout[(size_t)b * DX + d] = x;   // exact f32 final x
    } else if (tid < UCOLS) {
        for (int i = 0; i < NSTEP; ++i) {
            size_t p = ((size_t)(b * NSTEP + i)) * 2;
            float v0 = 0.f, v1 = 0.f;
            if (tid == 100) { v0 = DT_ * (float)i; v1 = DT_ * (float)(i + 1); }
            U[p * UCOLS + tid]       = __float2bfloat16(v0);
            U[(p + 1) * UCOLS + tid] = __float2bfloat16(v1);
        }
    }
}

// ---------------------------------------------------------------------------
// Weight fragment packing: W[Kact][Nact] f32 -> bf16 A-frags of W^T.
// frag idx = ((t*KC + c)*64 + lane)*8 + j ; n = t*16+(lane&15), k = c*32+(lane>>4)*8+j
// Out-of-range (k,n) -> 0 (handles K=101->128 and N=100->128 padding).
// ---------------------------------------------------------------------------
__global__ __launch_bounds__(256) void wpack_kernel(
    const float* __restrict__ W, bf16* __restrict__ dst,
    int Kact, int Nact, int KC, int total)
{
    int idx = blockIdx.x * 256 + threadIdx.x;
    if (idx >= total) return;
    int j = idx & 7;
    int l = (idx >> 3) & 63;
    int c = (idx >> 9) % KC;
    int t = idx / (KC * 512);
    int n = t * 16 + (l & 15);
    int k = c * 32 + (l >> 4) * 8 + j;
    float v = (k < Kact && n < Nact) ? W[(size_t)k * Nact + n] : 0.f;
    dst[idx] = __float2bfloat16(v);
}

// Pack biases into one padded f32 buffer: [0:256)=bi [256:512)=bh1 [512:768)=bh2 [768:896)=bo(pad0)
__global__ __launch_bounds__(256) void bpack_kernel(
    const float* __restrict__ bi, const float* __restrict__ bh1,
    const float* __restrict__ bh2, const float* __restrict__ bo,
    float* __restrict__ dst)
{
    int i = blockIdx.x * 256 + threadIdx.x;
    if (i < 256) dst[i] = bi[i];
    else if (i < 512) dst[i] = bh1[i - 256];
    else if (i < 768) dst[i] = bh2[i - 512];
    else if (i < 896) dst[i] = (i - 768 < DD) ? bo[i - 768] : 0.f;
}

// ---------------------------------------------------------------------------
// One MFMA layer, IN PLACE in a single LDS buffer, over MT m-tiles (MT*16 rows).
// A-frags (weights) are loaded once per c-iter and reused across all MT m-tiles
// (2x the MFMA cover per L2 load vs MT=4) with an explicit 1-deep prefetch.
//   phase 1: accumulate into registers (reads buf)
//   __syncthreads() -> all reads done block-wide
//   phase 2: bias+relu+pack, store back into buf (possibly new stride)
// Caller must __syncthreads() after return before the next layer reads.
// Wave w owns n-tiles [w*NT, w*NT+NT), all MT m-tiles.
// ---------------------------------------------------------------------------
template<int KC, int NT, int MT, int SRC_STRIDE, int DST_STRIDE, bool RELU>
__device__ __forceinline__ void layer_ip(
    char* __restrict__ buf,
    const bf16* __restrict__ wfrag, const float* __restrict__ bias,
    int lane, int w)
{
    const int lrow = lane & 15;   // m_local (B col) / n_local (A row)
    const int lkg  = lane >> 4;   // k-group
    f32x4 acc[NT][MT];
#pragma unroll
    for (int t = 0; t < NT; ++t)
#pragma unroll
        for (int mt = 0; mt < MT; ++mt) acc[t][mt] = (f32x4){0.f, 0.f, 0.f, 0.f};

    const char* wptr = (const char*)wfrag + ((size_t)(w * NT) * KC * 64 + lane) * 16;

    bf16x8v a_cur[NT];
#pragma unroll
    for (int t = 0; t < NT; ++t)
        a_cur[t] = *(const bf16x8v*)(wptr + (size_t)(t * KC) * 1024);

#pragma unroll
    for (int c = 0; c < KC; ++c) {
        bf16x8v b[MT];
#pragma unroll
        for (int mt = 0; mt < MT; ++mt) {
            int m = mt * 16 + lrow;
            b[mt] = *(const bf16x8v*)(buf + m * SRC_STRIDE +
                                      ((c * 64 + lkg * 16) ^ ((m & 7) << 4)));
        }
        bf16x8v a_nxt[NT];
        if (c + 1 < KC) {
#pragma unroll
            for (int t = 0; t < NT; ++t)
                a_nxt[t] = *(const bf16x8v*)(wptr + (size_t)(t * KC + c + 1) * 1024);
        }
        __builtin_amdgcn_s_setprio(1);
#pragma unroll
        for (int t = 0; t < NT; ++t)
#pragma unroll
            for (int mt = 0; mt < MT; ++mt)
                acc[t][mt] = __builtin_amdgcn_mfma_f32_16x16x32_bf16(a_cur[t], b[mt], acc[t][mt], 0, 0, 0);
        __builtin_amdgcn_s_setprio(0);
        if (c + 1 < KC) {
#pragma unroll
            for (int t = 0; t < NT; ++t) a_cur[t] = a_nxt[t];
        }
    }

    __syncthreads();   // all reads of buf complete block-wide; safe to overwrite

#pragma unroll
    for (int t = 0; t < NT; ++t) {
        const int nb = (w * NT + t) * 16 + lkg * 4;   // first of 4 consecutive features
        const float4 bv = *(const float4*)(bias + nb);
#pragma unroll
        for (int mt = 0; mt < MT; ++mt) {
            const int m = mt * 16 + lrow;
            float v0 = acc[t][mt][0] + bv.x;
            float v1 = acc[t][mt][1] + bv.y;
            float v2 = acc[t][mt][2] + bv.z;
            float v3 = acc[t][mt][3] + bv.w;
            if (RELU) {
                v0 = fmaxf(v0, 0.f); v1 = fmaxf(v1, 0.f);
                v2 = fmaxf(v2, 0.f); v3 = fmaxf(v3, 0.f);
            }
            bf16 h0 = __float2bfloat16(v0), h1 = __float2bfloat16(v1);
            bf16 h2 = __float2bfloat16(v2), h3 = __float2bfloat16(v3);
            short4v pv;
            pv[0] = *(short*)&h0; pv[1] = *(short*)&h1;
            pv[2] = *(short*)&h2; pv[3] = *(short*)&h3;
            *(short4v*)(buf + m * DST_STRIDE + ((nb * 2) ^ ((m & 7) << 4))) = pv;
        }
    }
}

// ---------------------------------------------------------------------------
// Kernel 2: fused 4-layer MFMA MLP over 128 rows + per-pair y-increment.
// 128 rows/block: each a-frag (L2) feeds 8 m-tiles = 32 MFMAs/c-iter (2x cover
// vs 64-row version); weight L2 traffic halves. acc[4][8]=128 regs ->
// __launch_bounds__(256,2) (~230 regs total, no spill; watch WRITE_SIZE).
// LDS 66KB -> 2 blocks/CU = 2 waves/SIMD.
// ---------------------------------------------------------------------------
__global__ __launch_bounds__(256, 2) void mlp_mfma_kernel(
    const bf16* __restrict__ U,
    const float* __restrict__ Wn, const int* __restrict__ signs,
    const bf16* __restrict__ wfWi, const bf16* __restrict__ wfWh1,
    const bf16* __restrict__ wfWh2, const bf16* __restrict__ wfWo,
    const float* __restrict__ biases, float* __restrict__ incr)
{
    __shared__ char buf[128 * 512];
    __shared__ float Sz2[128], Szw[128];
    const int tid = threadIdx.x;
    const int lane = tid & 63, w = tid >> 6;
    const size_t row0 = (size_t)blockIdx.x * 128;

    // Load U tile: 128 rows x 104 bf16 = 13 x 16B chunks/row -> buf [128][128]
    // stride 256B, swizzled; chunks 13..15 zero-filled (k padding must be 0).
    {
        const char* usrc = (const char*)(U + row0 * UCOLS);
        for (int idx = tid; idx < 2048; idx += 256) {
            int r = idx >> 4, c = idx & 15;
            uint4 v = (uint4){0, 0, 0, 0};
            if (c < 13) v = *(const uint4*)(usrc + r * 208 + c * 16);
            *(uint4*)(buf + r * 256 + ((c * 16) ^ ((r & 7) << 4))) = v;
        }
    }
    __syncthreads();

    layer_ip<4, 4, 8, 256, 512, true >(buf, wfWi,  biases,        lane, w);
    __syncthreads();
    layer_ip<8, 4, 8, 512, 512, true >(buf, wfWh1, biases + 256,  lane, w);
    __syncthreads();
    layer_ip<8, 4, 8, 512, 512, true >(buf, wfWh2, biases + 512,  lane, w);
    __syncthreads();
    layer_ip<8, 2, 8, 512, 256, false>(buf, wfWo,  biases + 768,  lane, w);
    __syncthreads();
    // z rows now in buf [128][128] stride 256B (features 0..99 valid)

    // Per-row reductions: 4 threads per row, two passes of 64 rows
    const int q = tid & 3;
#pragma unroll
    for (int half = 0; half < 2; ++half) {
        const int r = (tid >> 2) + half * 64;
        const size_t g = row0 + r;
        const size_t pair = g >> 1;
        const int h = (int)(g & 1);
        const int bb = (int)(pair >> 7), ii = (int)(pair & 127);
        const float s = 2.f * (float)signs[ii] - 1.f;
        const float sdt = s * SQDT_;
        const float* wb = Wn + (size_t)bb * DD * NSTEP + ii;

        float sz2 = 0.f, szw = 0.f;
        for (int d = q; d < DD; d += 4) {
            unsigned short zb = *(const unsigned short*)(buf + r * 256 + ((d * 2) ^ ((r & 7) << 4)));
            union { unsigned int u; float f; } cv; cv.u = ((unsigned int)zb) << 16;
            float z = cv.f;
            float wv = SQDT_ * wb[(size_t)d * NSTEP];
            float wt = h ? (wv + sdt) : (wv - sdt);
            sz2 += z * z;
            szw += z * wt;
        }
        sz2 += __shfl_xor(sz2, 1); sz2 += __shfl_xor(sz2, 2);
        szw += __shfl_xor(szw, 1); szw += __shfl_xor(szw, 2);
        if (q == 0) { Sz2[r] = sz2; Szw[r] = szw; }
    }
    __syncthreads();

    // incr = -||z||^2*dt + 0.5*(z.(w-sdt) + z_new.(w+sdt));  z from h=0 row
    if (tid < 64) {
        int rr = tid * 2;
        incr[row0 / 2 + tid] = -Sz2[rr] * DT_ + 0.5f * (Szw[rr] + Szw[rr + 1]);
    }
}

// ---------------------------------------------------------------------------
// Kernel 3: y[b] = y0 + sum_i incr[b*128+i]
// ---------------------------------------------------------------------------
__global__ __launch_bounds__(128) void y_kernel(
    const float* __restrict__ incr, const float* __restrict__ y0,
    float* __restrict__ yout)
{
    const int b = blockIdx.x, tid = threadIdx.x;
    float v = incr[(size_t)b * NSTEP + tid];
#pragma unroll
    for (int off = 1; off < 64; off <<= 1) v += __shfl_xor(v, off);
    __shared__ float partial[2];
    if ((tid & 63) == 0) partial[tid >> 6] = v;
    __syncthreads();
    if (tid == 0) yout[b] = y0[0] + partial[0] + partial[1];
}

// ---------------------------------------------------------------------------
extern "C" void kernel_launch(void* const* d_in, const int* in_sizes, int n_in,
                              void* d_out, int out_size, void* d_ws, size_t ws_size,
                              hipStream_t stream) {
    (void)in_sizes; (void)n_in; (void)out_size; (void)ws_size;
    const float* Wn    = (const float*)d_in[0];
    const int*   signs = (const int*)d_in[1];
    const float* x0    = (const float*)d_in[2];
    const float* y0    = (const float*)d_in[3];
    const float* Wi    = (const float*)d_in[4];
    const float* bi    = (const float*)d_in[5];
    const float* Wh1   = (const float*)d_in[6];
    const float* bh1   = (const float*)d_in[7];
    const float* Wh2   = (const float*)d_in[8];
    const float* bh2   = (const float*)d_in[9];
    const float* Wo    = (const float*)d_in[10];
    const float* bo    = (const float*)d_in[11];

    float* out  = (float*)d_out;
    float* xout = out;                       // [2048,100]
    float* yout = out + (size_t)B_SZ * DX;   // [2048,1]

    const size_t NROWS = (size_t)B_SZ * NSTEP * 2;           // 524288
    char* ws = (char*)d_ws;
    size_t off = 0;
    bf16*  U      = (bf16*)(ws + off); off += NROWS * UCOLS * sizeof(bf16);   // ~109 MB
    float* incr   = (float*)(ws + off); off += (NROWS / 2) * sizeof(float);   // 1 MB
    bf16*  wfWi   = (bf16*)(ws + off); off += 32768 * sizeof(bf16);
    bf16*  wfWh1  = (bf16*)(ws + off); off += 65536 * sizeof(bf16);
    bf16*  wfWh2  = (bf16*)(ws + off); off += 65536 * sizeof(bf16);
    bf16*  wfWo   = (bf16*)(ws + off); off += 32768 * sizeof(bf16);
    float* biases = (float*)(ws + off); off += 896 * sizeof(float);

    prep_kernel<<<B_SZ, 128, 0, stream>>>(Wn, signs, x0, U, xout);
    wpack_kernel<<<128, 256, 0, stream>>>(Wi,  wfWi,  101, 256, 4, 32768);
    wpack_kernel<<<256, 256, 0, stream>>>(Wh1, wfWh1, 256, 256, 8, 65536);
    wpack_kernel<<<256, 256, 0, stream>>>(Wh2, wfWh2, 256, 256, 8, 65536);
    wpack_kernel<<<128, 256, 0, stream>>>(Wo,  wfWo,  256, 100, 8, 32768);
    bpack_kernel<<<4, 256, 0, stream>>>(bi, bh1, bh2, bo, biases);

    mlp_mfma_kernel<<<(int)(NROWS / 128), 256, 0, stream>>>(
        U, Wn, signs, wfWi, wfWh1, wfWh2, wfWo, biases, incr);
    y_kernel<<<B_SZ, 128, 0, stream>>>(incr, y0, yout);
}